// Round 6
// baseline (110.538 us; speedup 1.0000x reference)
//
#include <hip/hip_runtime.h>

// CompiledLogicNet fully fused: one block per u32 batch-column (32 samples).
// State [16384] u32 (16000 padded) in LDS, double-buffered. Gathers = LDS reads.
// Thread t owns 4 groups of 4 consecutive gates -> ds_write_b128 stores.
// Prep: balance_kernel greedily swaps (a,b) per gate (AND commutes) to even
// out LDS bank loads within each 64-lane read wave-op. GroupSum: one wave per
// class, b128 reads + CSA planes + shfl_xor butterfly (no barriers).

#define NIN   784
#define WIDTH 16000
#define SW    16384    // padded width (16 * TPB)
#define NH    4
#define NC    10
#define GPC   1600     // gates per class
#define NBLK  128      // u32 columns: 4096 batch / 32
#define TPB   1024

typedef unsigned int u32;

// ---------------------------------------------------------------------------
// Pack (idx_a, idx_b, neg) -> desc[l][g] = ia | ib<<14 | na<<28 | nb<<29,
// padded to SW per layer (pad gates: a=b=0, no neg -> harmless).
__global__ void desc_kernel(const int* __restrict__ ia0, const int* __restrict__ ib0,
                            const int* __restrict__ n0,
                            const int* __restrict__ ia, const int* __restrict__ ib,
                            const int* __restrict__ n, u32* __restrict__ desc) {
    int t = blockIdx.x * blockDim.x + threadIdx.x;
    if (t >= (NH + 1) * SW) return;
    int l = t >> 14;          // t / SW
    int g = t & (SW - 1);     // t % SW
    u32 d = 0;
    if (g < WIDTH) {
        int a, b, na, nb;
        if (l == 0) { a = ia0[g]; b = ib0[g]; na = n0[2 * g]; nb = n0[2 * g + 1]; }
        else {
            int o = (l - 1) * WIDTH + g;
            a = ia[o]; b = ib[o]; na = n[2 * o]; nb = n[2 * o + 1];
        }
        d = (u32)a | ((u32)b << 14) | (na ? (1u << 28) : 0u) | (nb ? (1u << 29) : 0u);
    }
    desc[t] = d;
}

// ---------------------------------------------------------------------------
// Greedy a/b swap balancing. One unit per (layer l, wave w0, uint4-slot j,
// element e): the 64 gates read together in one LDS gather wave-op.
// Private nibble counters (32 banks x 2 ops) in LDS.
#define BAL_TPB 256
__global__ void balance_kernel(u32* __restrict__ desc) {
    int u = blockIdx.x * blockDim.x + threadIdx.x;
    if (u >= 5 * 16 * 4 * 4) return;
    int e  = u & 3;
    int j  = (u >> 2) & 3;
    int w0 = (u >> 4) & 15;
    int l  = u >> 8;
    __shared__ u32 cnt[BAL_TPB][16];  // [0..7]=cntA nibbles, [8..15]=cntB
    u32* cA = cnt[threadIdx.x];
    u32* cB = cnt[threadIdx.x] + 8;
#pragma unroll
    for (int q = 0; q < 16; ++q) cnt[threadIdx.x][q] = 0;
    u32* dp = desc + (size_t)l * SW;
    for (int L = 0; L < 64; ++L) {
        int g = 4 * (w0 * 64 + L + 1024 * j) + e;
        u32 d = dp[g];
        u32 a = d & 0x3FFFu, b = (d >> 14) & 0x3FFFu;
        int ba = (int)(a & 31u), bb = (int)(b & 31u);
        u32 nAa = (cA[ba >> 3] >> ((ba & 7) * 4)) & 15u;
        u32 nBb = (cB[bb >> 3] >> ((bb & 7) * 4)) & 15u;
        u32 nAb = (cA[bb >> 3] >> ((bb & 7) * 4)) & 15u;
        u32 nBa = (cB[ba >> 3] >> ((ba & 7) * 4)) & 15u;
        u32 costN = (nAa > nBb ? nAa : nBb) * 16u + nAa + nBb;
        u32 costS = (nAb > nBa ? nAb : nBa) * 16u + nAb + nBa;
        if (costS < costN) {
            u32 na = (d >> 28) & 1u, nb = (d >> 29) & 1u;
            d = b | (a << 14) | (nb << 28) | (na << 29);
            dp[g] = d;
            int tm = ba; ba = bb; bb = tm;
        }
        if (((cA[ba >> 3] >> ((ba & 7) * 4)) & 15u) < 15u) cA[ba >> 3] += 1u << ((ba & 7) * 4);
        if (((cB[bb >> 3] >> ((bb & 7) * 4)) & 15u) < 15u) cB[bb >> 3] += 1u << ((bb & 7) * 4);
    }
}

// ---------------------------------------------------------------------------
__launch_bounds__(TPB)
__global__ void net_kernel(const int* __restrict__ x, const u32* __restrict__ desc,
                           int* __restrict__ out) {
    __shared__ __align__(16) u32 xw[NIN];
    __shared__ __align__(16) u32 bufA[SW];
    __shared__ __align__(16) u32 bufB[SW];

    int w = blockIdx.x;
    int t = threadIdx.x;

    // prefetch layer-0 descriptors (4 x dwordx4) while we pack
    uint4 dreg[4];
    {
        const uint4* d0 = (const uint4*)desc;
#pragma unroll
        for (int j = 0; j < 4; ++j) dreg[j] = d0[t + j * TPB];
    }

    // ---- pack: xw[i] bit r = x[w*32+r][i] (coalesced along i) ----
    if (t < NIN) {
        const int* base = x + (size_t)(w * 32) * NIN + t;
        u32 acc = 0;
#pragma unroll
        for (int r = 0; r < 32; ++r)
            acc |= (base[(size_t)r * NIN] != 0 ? 1u : 0u) << r;
        xw[t] = acc;
    }
    __syncthreads();

    // ---- 5 layers, ping-pong LDS ----
    u32* cur = xw;
#pragma unroll
    for (int l = 0; l <= NH; ++l) {
        u32* dst = (l & 1) ? bufB : bufA;   // A,B,A,B,A -> result in bufA
        uint4 dn[4];
        if (l < NH) {
            const uint4* dq = (const uint4*)(desc + (size_t)(l + 1) * SW);
#pragma unroll
            for (int j = 0; j < 4; ++j) dn[j] = dq[t + j * TPB];
        }
#pragma unroll
        for (int j = 0; j < 4; ++j) {
            u32 d0 = dreg[j].x, d1 = dreg[j].y, d2 = dreg[j].z, d3 = dreg[j].w;
            u32 a0 = cur[d0 & 0x3FFFu], b0 = cur[(d0 >> 14) & 0x3FFFu];
            u32 a1 = cur[d1 & 0x3FFFu], b1 = cur[(d1 >> 14) & 0x3FFFu];
            u32 a2 = cur[d2 & 0x3FFFu], b2 = cur[(d2 >> 14) & 0x3FFFu];
            u32 a3 = cur[d3 & 0x3FFFu], b3 = cur[(d3 >> 14) & 0x3FFFu];
            uint4 r;
            r.x = (a0 ^ (0u - ((d0 >> 28) & 1u))) & (b0 ^ (0u - ((d0 >> 29) & 1u)));
            r.y = (a1 ^ (0u - ((d1 >> 28) & 1u))) & (b1 ^ (0u - ((d1 >> 29) & 1u)));
            r.z = (a2 ^ (0u - ((d2 >> 28) & 1u))) & (b2 ^ (0u - ((d2 >> 29) & 1u)));
            r.w = (a3 ^ (0u - ((d3 >> 28) & 1u))) & (b3 ^ (0u - ((d3 >> 29) & 1u)));
            *(uint4*)(dst + 4 * (t + j * TPB)) = r;   // ds_write_b128, conflict-free
        }
        __syncthreads();
#pragma unroll
        for (int j = 0; j < 4; ++j) dreg[j] = dn[j];
        cur = dst;
    }
    u32* res = bufA;

    // ---- GroupSum: one wave per class, CSA planes + shfl_xor butterfly ----
    int wave = t >> 6, lane = t & 63;
    if (wave < NC) {
        int c = wave;
        const u32* base = res + c * GPC;
        u32 p0 = 0, p1 = 0, p2 = 0, p3 = 0, p4 = 0;
#define CSA5(VAL) { u32 cy = (VAL); u32 s; \
        s = p0; p0 = s ^ cy; cy = s & cy; \
        s = p1; p1 = s ^ cy; cy = s & cy; \
        s = p2; p2 = s ^ cy; cy = s & cy; \
        s = p3; p3 = s ^ cy; cy = s & cy; \
        s = p4; p4 = s ^ cy; }
#pragma unroll
        for (int k = 0; k < 6; ++k) {
            uint4 v = *(const uint4*)(base + 4 * lane + 256 * k);  // b128, conflict-free
            CSA5(v.x); CSA5(v.y); CSA5(v.z); CSA5(v.w);
        }
        CSA5(base[1536 + lane]);   // 25 values per lane, fits 5 planes
#undef CSA5

        // butterfly: merge 64 lanes' plane sets; planes grow 5 -> 11
        u32 pl[11];
        pl[0] = p0; pl[1] = p1; pl[2] = p2; pl[3] = p3; pl[4] = p4;
#pragma unroll
        for (int s = 0; s < 6; ++s) {
            int np = 5 + s;
            u32 q[11];
#pragma unroll
            for (int i = 0; i < 11; ++i) if (i < np) q[i] = __shfl_xor(pl[i], 1 << s, 64);
            u32 carry = 0;
#pragma unroll
            for (int i = 0; i < 11; ++i) if (i < np) {
                u32 a = pl[i], b = q[i];
                u32 xr = a ^ b;
                pl[i] = xr ^ carry;
                carry = (a & b) | (carry & xr);
            }
            pl[np] = carry;
        }

        // every lane now holds the 11-plane vertical count over 1600 gates
        if (lane < 32) {
            int cntv = 0;
#pragma unroll
            for (int i = 0; i < 11; ++i) cntv += (int)((pl[i] >> lane) & 1u) << i;
            out[((size_t)w * 32 + lane) * NC + c] = cntv;
        }
    }
}

// ---------------------------------------------------------------------------
extern "C" void kernel_launch(void* const* d_in, const int* in_sizes, int n_in,
                              void* d_out, int out_size, void* d_ws, size_t ws_size,
                              hipStream_t stream) {
    const int* x      = (const int*)d_in[0];  // [4096,784] 0/1
    const int* idx_a0 = (const int*)d_in[1];  // [16000]
    const int* idx_b0 = (const int*)d_in[2];  // [16000]
    const int* neg0   = (const int*)d_in[3];  // [16000,2]
    const int* idx_a  = (const int*)d_in[4];  // [4,16000]
    const int* idx_b  = (const int*)d_in[5];  // [4,16000]
    const int* neg    = (const int*)d_in[6];  // [4,16000,2]
    int* out = (int*)d_out;                   // [4096,10]

    u32* desc = (u32*)d_ws;                   // (NH+1)*SW*4 = 327,680 B

    int ndesc = (NH + 1) * SW;
    desc_kernel<<<(ndesc + 255) / 256, 256, 0, stream>>>(
        idx_a0, idx_b0, neg0, idx_a, idx_b, neg, desc);

    int nbal = 5 * 16 * 4 * 4;  // 1280 balance units
    balance_kernel<<<(nbal + BAL_TPB - 1) / BAL_TPB, BAL_TPB, 0, stream>>>(desc);

    net_kernel<<<NBLK, TPB, 0, stream>>>(x, desc, out);
}

// Round 7
// 86.038 us; speedup vs baseline: 1.2848x; 1.2848x over previous
//
#include <hip/hip_runtime.h>

// CompiledLogicNet fully fused: one block per u32 batch-column (32 samples).
// State [16384] u32 (16000 padded) in LDS, double-buffered. Gathers = LDS reads.
// Thread t owns 4 groups of 4 consecutive gates; per layer ALL 32 gather reads
// are issued before any consume (max DS-queue depth), then 4 ds_write_b128.
// GroupSum: one wave per class, b128 reads + CSA planes + shfl_xor butterfly.

#define NIN   784
#define WIDTH 16000
#define SW    16384    // padded width (16 * TPB)
#define NH    4
#define NC    10
#define GPC   1600     // gates per class
#define NBLK  128      // u32 columns: 4096 batch / 32
#define TPB   1024

typedef unsigned int u32;

// ---------------------------------------------------------------------------
// Pack (idx_a, idx_b, neg) -> desc[l][g] = ia | ib<<14 | na<<28 | nb<<29,
// padded to SW per layer (pad gates: a=b=0, no neg -> harmless).
__global__ void desc_kernel(const int* __restrict__ ia0, const int* __restrict__ ib0,
                            const int* __restrict__ n0,
                            const int* __restrict__ ia, const int* __restrict__ ib,
                            const int* __restrict__ n, u32* __restrict__ desc) {
    int t = blockIdx.x * blockDim.x + threadIdx.x;
    if (t >= (NH + 1) * SW) return;
    int l = t >> 14;          // t / SW
    int g = t & (SW - 1);     // t % SW
    u32 d = 0;
    if (g < WIDTH) {
        int a, b, na, nb;
        if (l == 0) { a = ia0[g]; b = ib0[g]; na = n0[2 * g]; nb = n0[2 * g + 1]; }
        else {
            int o = (l - 1) * WIDTH + g;
            a = ia[o]; b = ib[o]; na = n[2 * o]; nb = n[2 * o + 1];
        }
        d = (u32)a | ((u32)b << 14) | (na ? (1u << 28) : 0u) | (nb ? (1u << 29) : 0u);
    }
    desc[t] = d;
}

// ---------------------------------------------------------------------------
__launch_bounds__(TPB, 4)
__global__ void net_kernel(const int* __restrict__ x, const u32* __restrict__ desc,
                           int* __restrict__ out) {
    __shared__ __align__(16) u32 xw[NIN];
    __shared__ __align__(16) u32 bufA[SW];
    __shared__ __align__(16) u32 bufB[SW];

    int w = blockIdx.x;
    int t = threadIdx.x;

    // prefetch layer-0 descriptors (4 x dwordx4) while we pack
    uint4 dreg[4];
    {
        const uint4* d0 = (const uint4*)desc;
#pragma unroll
        for (int j = 0; j < 4; ++j) dreg[j] = d0[t + j * TPB];
    }

    // ---- pack: xw[i] bit r = x[w*32+r][i] (coalesced along i) ----
    if (t < NIN) {
        const int* base = x + (size_t)(w * 32) * NIN + t;
        u32 acc = 0;
#pragma unroll
        for (int r = 0; r < 32; ++r)
            acc |= (base[(size_t)r * NIN] != 0 ? 1u : 0u) << r;
        xw[t] = acc;
    }
    __syncthreads();

    // ---- 5 layers, ping-pong LDS ----
    u32* cur = xw;
#pragma unroll
    for (int l = 0; l <= NH; ++l) {
        u32* dst = (l & 1) ? bufB : bufA;   // A,B,A,B,A -> result in bufA
        uint4 dn[4];
        if (l < NH) {
            const uint4* dq = (const uint4*)(desc + (size_t)(l + 1) * SW);
#pragma unroll
            for (int j = 0; j < 4; ++j) dn[j] = dq[t + j * TPB];
        }
        // Phase 1: issue ALL 32 gather reads (no consume in between)
        u32 av[16], bv[16];
#pragma unroll
        for (int j = 0; j < 4; ++j) {
            u32 d0 = dreg[j].x, d1 = dreg[j].y, d2 = dreg[j].z, d3 = dreg[j].w;
            av[4 * j + 0] = cur[d0 & 0x3FFFu]; bv[4 * j + 0] = cur[(d0 >> 14) & 0x3FFFu];
            av[4 * j + 1] = cur[d1 & 0x3FFFu]; bv[4 * j + 1] = cur[(d1 >> 14) & 0x3FFFu];
            av[4 * j + 2] = cur[d2 & 0x3FFFu]; bv[4 * j + 2] = cur[(d2 >> 14) & 0x3FFFu];
            av[4 * j + 3] = cur[d3 & 0x3FFFu]; bv[4 * j + 3] = cur[(d3 >> 14) & 0x3FFFu];
        }
        // Phase 2: compute + vectorized stores
#pragma unroll
        for (int j = 0; j < 4; ++j) {
            u32 d0 = dreg[j].x, d1 = dreg[j].y, d2 = dreg[j].z, d3 = dreg[j].w;
            uint4 r;
            r.x = (av[4 * j + 0] ^ (0u - ((d0 >> 28) & 1u))) & (bv[4 * j + 0] ^ (0u - ((d0 >> 29) & 1u)));
            r.y = (av[4 * j + 1] ^ (0u - ((d1 >> 28) & 1u))) & (bv[4 * j + 1] ^ (0u - ((d1 >> 29) & 1u)));
            r.z = (av[4 * j + 2] ^ (0u - ((d2 >> 28) & 1u))) & (bv[4 * j + 2] ^ (0u - ((d2 >> 29) & 1u)));
            r.w = (av[4 * j + 3] ^ (0u - ((d3 >> 28) & 1u))) & (bv[4 * j + 3] ^ (0u - ((d3 >> 29) & 1u)));
            *(uint4*)(dst + 4 * (t + j * TPB)) = r;   // ds_write_b128, conflict-free
        }
        __syncthreads();
#pragma unroll
        for (int j = 0; j < 4; ++j) dreg[j] = dn[j];
        cur = dst;
    }
    u32* res = bufA;

    // ---- GroupSum: one wave per class, CSA planes + shfl_xor butterfly ----
    int wave = t >> 6, lane = t & 63;
    if (wave < NC) {
        int c = wave;
        const u32* base = res + c * GPC;
        u32 p0 = 0, p1 = 0, p2 = 0, p3 = 0, p4 = 0;
#define CSA5(VAL) { u32 cy = (VAL); u32 s; \
        s = p0; p0 = s ^ cy; cy = s & cy; \
        s = p1; p1 = s ^ cy; cy = s & cy; \
        s = p2; p2 = s ^ cy; cy = s & cy; \
        s = p3; p3 = s ^ cy; cy = s & cy; \
        s = p4; p4 = s ^ cy; }
#pragma unroll
        for (int k = 0; k < 6; ++k) {
            uint4 v = *(const uint4*)(base + 4 * lane + 256 * k);  // b128, conflict-free
            CSA5(v.x); CSA5(v.y); CSA5(v.z); CSA5(v.w);
        }
        CSA5(base[1536 + lane]);   // 25 values per lane, fits 5 planes
#undef CSA5

        // butterfly: merge 64 lanes' plane sets; planes grow 5 -> 11
        u32 pl[11];
        pl[0] = p0; pl[1] = p1; pl[2] = p2; pl[3] = p3; pl[4] = p4;
#pragma unroll
        for (int s = 0; s < 6; ++s) {
            int np = 5 + s;
            u32 q[11];
#pragma unroll
            for (int i = 0; i < 11; ++i) if (i < np) q[i] = __shfl_xor(pl[i], 1 << s, 64);
            u32 carry = 0;
#pragma unroll
            for (int i = 0; i < 11; ++i) if (i < np) {
                u32 a = pl[i], b = q[i];
                u32 xr = a ^ b;
                pl[i] = xr ^ carry;
                carry = (a & b) | (carry & xr);
            }
            pl[np] = carry;
        }

        // every lane now holds the 11-plane vertical count over 1600 gates
        if (lane < 32) {
            int cntv = 0;
#pragma unroll
            for (int i = 0; i < 11; ++i) cntv += (int)((pl[i] >> lane) & 1u) << i;
            out[((size_t)w * 32 + lane) * NC + c] = cntv;
        }
    }
}

// ---------------------------------------------------------------------------
extern "C" void kernel_launch(void* const* d_in, const int* in_sizes, int n_in,
                              void* d_out, int out_size, void* d_ws, size_t ws_size,
                              hipStream_t stream) {
    const int* x      = (const int*)d_in[0];  // [4096,784] 0/1
    const int* idx_a0 = (const int*)d_in[1];  // [16000]
    const int* idx_b0 = (const int*)d_in[2];  // [16000]
    const int* neg0   = (const int*)d_in[3];  // [16000,2]
    const int* idx_a  = (const int*)d_in[4];  // [4,16000]
    const int* idx_b  = (const int*)d_in[5];  // [4,16000]
    const int* neg    = (const int*)d_in[6];  // [4,16000,2]
    int* out = (int*)d_out;                   // [4096,10]

    u32* desc = (u32*)d_ws;                   // (NH+1)*SW*4 = 327,680 B

    int ndesc = (NH + 1) * SW;
    desc_kernel<<<(ndesc + 255) / 256, 256, 0, stream>>>(
        idx_a0, idx_b0, neg0, idx_a, idx_b, neg, desc);

    net_kernel<<<NBLK, TPB, 0, stream>>>(x, desc, out);
}